// Round 5
// baseline (82.535 us; speedup 1.0000x reference)
//
#include <hip/hip_runtime.h>
#include <hip/hip_bf16.h>
#include <math.h>

#define NTOK 10000
#define BATCH 2
#define CDIM 128
#define NHEAD 4
#define NPNT 20
#define DHEAD 32
#define HWDIM 100
#define MROWS (BATCH * NTOK)
#define OCAT 368   // 128 value + 160 off + 80 attn
#define OPAD 384   // padded to 64-multiple
#define PTOK 8     // 8x8 tokens per patch
#define PHALO 4    // halo cells each side
#define PDIM 16    // PTOK + 2*PHALO
#define NPATCH 13  // ceil(100/8)
#define CELLPAD 40 // bf16 per cell in LDS (32 + 8 pad)

typedef __attribute__((ext_vector_type(8))) short short8v;
typedef __attribute__((ext_vector_type(4))) short short4v;
typedef __attribute__((ext_vector_type(4))) float f32x4;

__device__ __forceinline__ float asf(unsigned u) {
  union { unsigned u; float f; } c; c.u = u; return c.f;
}
__device__ __forceinline__ unsigned asu(float f) {
  union { float f; unsigned u; } c; c.f = f; return c.u;
}
// pack two floats as bf16 pair (RNE) into one u32: lo in bits 0-15, hi in 16-31
__device__ __forceinline__ unsigned pack_bf(float lo, float hi) {
  unsigned a = asu(lo), b = asu(hi);
  unsigned ar = (a + 0x7FFFu + ((a >> 16) & 1)) >> 16;
  unsigned br = (b + 0x7FFFu + ((b >> 16) & 1)) & 0xFFFF0000u;
  return (ar & 0xFFFFu) | br;
}

// ---------------------------------------------------------------------------
// Fold the two output projections: Wc = W2 @ W1, bc = b2 + W2 @ b1 (fp32)
// ---------------------------------------------------------------------------
__global__ __launch_bounds__(128) void fold_kernel(
    const float* __restrict__ W1, const float* __restrict__ b1,
    const float* __restrict__ W2, const float* __restrict__ b2,
    float* __restrict__ Wc, float* __restrict__ bc) {
  __shared__ float w2row[128];
  __shared__ float red[128];
  int o = blockIdx.x, c = threadIdx.x;
  w2row[c] = W2[o * 128 + c];
  __syncthreads();
  float acc = 0.f;
  for (int k = 0; k < 128; ++k) acc += w2row[k] * W1[k * 128 + c];
  Wc[o * 128 + c] = acc;
  red[c] = w2row[c] * b1[c];
  __syncthreads();
  for (int s = 64; s > 0; s >>= 1) {
    if (c < s) red[c] += red[c + s];
    __syncthreads();
  }
  if (c == 0) bc[o] = b2[o] + red[0];
}

// ---------------------------------------------------------------------------
// Convert weights to bf16: Wcat[384][128], bcat[384]; Wc fp32 -> Wc_bf.
// ---------------------------------------------------------------------------
__global__ __launch_bounds__(128) void conv_kernel(
    const float* __restrict__ W_val, const float* __restrict__ b_val,
    const float* __restrict__ W_off, const float* __restrict__ b_off,
    const float* __restrict__ W_attn, const float* __restrict__ b_attn,
    const float* __restrict__ Wc, __hip_bfloat16* __restrict__ Wcat,
    float* __restrict__ bcat, __hip_bfloat16* __restrict__ Wc_bf) {
  int r = blockIdx.x, c = threadIdx.x;
  if (r < OPAD) {
    float v = 0.f, bv = 0.f;
    if (r < 128) { v = W_val[r * 128 + c]; bv = b_val[r]; }
    else if (r < 288) { v = W_off[(r - 128) * 128 + c]; bv = b_off[r - 128]; }
    else if (r < OCAT) { v = W_attn[(r - 288) * 128 + c]; bv = b_attn[r - 288]; }
    Wcat[(size_t)r * 128 + c] = __float2bfloat16(v);
    if (c == 0) bcat[r] = bv;
  } else {
    int rr = r - OPAD;
    Wc_bf[(size_t)rr * 128 + c] = __float2bfloat16(Wc[rr * 128 + c]);
  }
}

// ---------------------------------------------------------------------------
// MFMA bf16 GEMM, internal W-tile loop (A staged+hoisted ONCE per block).
// Block: 64 rows x (Otiles x 64) outs, 4 waves 2x2, wave = 32x32 per tile.
// AKIND 0: A = fp32 src+src2 -> bf16.  AKIND 1: A = bf16 src.
// MODE 0: scatter to head-major value(bf16)/off/attn.  MODE 1: fp32 + resid.
// ---------------------------------------------------------------------------
template <int MODE, int AKIND>
__global__ __launch_bounds__(256) void mfma_proj_kernel(
    const float* __restrict__ src_f, const float* __restrict__ src2,
    const __hip_bfloat16* __restrict__ src_b,
    const __hip_bfloat16* __restrict__ Wb, const float* __restrict__ bias,
    __hip_bfloat16* __restrict__ value, float* __restrict__ offo,
    float* __restrict__ attno, float* __restrict__ out,
    const float* __restrict__ resid, int M, int Otiles, int Ototal) {
  __shared__ __hip_bfloat16 qa[64][128];
  __shared__ __hip_bfloat16 wb[64][128];
  const int t = threadIdx.x;
  const int r0 = blockIdx.x * 64;

#pragma unroll
  for (int i = 0; i < 4; ++i) {
    int lin = t + 256 * i;  // 0..1023
    int r = lin >> 4;       // row 0..63
    int g = lin & 15;       // 16B granule
    if (AKIND == 0) {
      int c = g << 3;
      float4 v0 = make_float4(0.f, 0.f, 0.f, 0.f);
      float4 v1 = make_float4(0.f, 0.f, 0.f, 0.f);
      if (r0 + r < M) {
        const float* p = src_f + (size_t)(r0 + r) * CDIM + c;
        v0 = *(const float4*)p;
        v1 = *(const float4*)(p + 4);
        const float* p2 = src2 + (size_t)(r0 + r) * CDIM + c;
        float4 u0 = *(const float4*)p2;
        float4 u1 = *(const float4*)(p2 + 4);
        v0.x += u0.x; v0.y += u0.y; v0.z += u0.z; v0.w += u0.w;
        v1.x += u1.x; v1.y += u1.y; v1.z += u1.z; v1.w += u1.w;
      }
      __hip_bfloat16* dst = &qa[r][(g ^ (r & 7)) << 3];
      dst[0] = __float2bfloat16(v0.x); dst[1] = __float2bfloat16(v0.y);
      dst[2] = __float2bfloat16(v0.z); dst[3] = __float2bfloat16(v0.w);
      dst[4] = __float2bfloat16(v1.x); dst[5] = __float2bfloat16(v1.y);
      dst[6] = __float2bfloat16(v1.z); dst[7] = __float2bfloat16(v1.w);
    } else {
      short8v v = (short8v)(short)0;
      if (r0 + r < M)
        v = *(const short8v*)(src_b + (size_t)(r0 + r) * CDIM + (g << 3));
      *(short8v*)&qa[r][(g ^ (r & 7)) << 3] = v;
    }
  }
  __syncthreads();

  const int wid = t >> 6;
  const int lane = t & 63;
  const int wr = (wid >> 1) * 32;
  const int wc = (wid & 1) * 32;
  const int lrow = lane & 15;
  const int lk = lane >> 4;

  // hoist A fragments (reused across all W tiles)
  short8v afr[4][2];
  {
    int ra0 = wr + lrow, ra1 = wr + 16 + lrow;
#pragma unroll
    for (int kk = 0; kk < 4; ++kk) {
      int gb = kk * 4 + lk;
      afr[kk][0] = *(const short8v*)&qa[ra0][(gb ^ (ra0 & 7)) << 3];
      afr[kk][1] = *(const short8v*)&qa[ra1][(gb ^ (ra1 & 7)) << 3];
    }
  }

  for (int ti = 0; ti < Otiles; ++ti) {
    const int ot = ti * 64;
    __syncthreads();  // previous tile's MFMA readers done
#pragma unroll
    for (int i = 0; i < 4; ++i) {
      int lin = t + 256 * i;
      int r = lin >> 4;
      int g = lin & 15;
      short8v w = *(const short8v*)(Wb + (size_t)(ot + r) * 128 + (g << 3));
      *(short8v*)&wb[r][(g ^ (r & 7)) << 3] = w;
    }
    __syncthreads();

    f32x4 acc[2][2];
#pragma unroll
    for (int mi = 0; mi < 2; ++mi)
#pragma unroll
      for (int ni = 0; ni < 2; ++ni) acc[mi][ni] = (f32x4)(0.f);

#pragma unroll
    for (int kk = 0; kk < 4; ++kk) {
      const int gb = kk * 4 + lk;
      int rb0 = wc + lrow, rb1 = wc + 16 + lrow;
      short8v b0 = *(const short8v*)&wb[rb0][(gb ^ (rb0 & 7)) << 3];
      short8v b1 = *(const short8v*)&wb[rb1][(gb ^ (rb1 & 7)) << 3];
      acc[0][0] = __builtin_amdgcn_mfma_f32_16x16x32_bf16(afr[kk][0], b0, acc[0][0], 0, 0, 0);
      acc[0][1] = __builtin_amdgcn_mfma_f32_16x16x32_bf16(afr[kk][0], b1, acc[0][1], 0, 0, 0);
      acc[1][0] = __builtin_amdgcn_mfma_f32_16x16x32_bf16(afr[kk][1], b0, acc[1][0], 0, 0, 0);
      acc[1][1] = __builtin_amdgcn_mfma_f32_16x16x32_bf16(afr[kk][1], b1, acc[1][1], 0, 0, 0);
    }

    // C/D: col = lane&15, row = (lane>>4)*4 + reg
#pragma unroll
    for (int mi = 0; mi < 2; ++mi) {
#pragma unroll
      for (int ni = 0; ni < 2; ++ni) {
#pragma unroll
        for (int reg = 0; reg < 4; ++reg) {
          int r = r0 + wr + mi * 16 + (lane >> 4) * 4 + reg;
          int o = ot + wc + ni * 16 + (lane & 15);
          if (r >= M || o >= Ototal) continue;
          float v = acc[mi][ni][reg] + bias[o];
          if (MODE == 1) {
            out[(size_t)r * CDIM + o] = v + resid[(size_t)r * CDIM + o];
          } else {
            int b = r >= NTOK ? 1 : 0;
            int n = r - b * NTOK;
            if (o < 128) {
              int h = o >> 5, rem = o & 31;
              value[(((size_t)b * NHEAD + h) * NTOK + n) * 32 + rem] =
                  __float2bfloat16(v);
            } else if (o < 288) {
              int oo = o - 128, h = oo / 40, rem = oo - h * 40;
              offo[(((size_t)b * NHEAD + h) * NTOK + n) * 40 + rem] = v;
            } else {
              int oo = o - 288, h = oo / 20, rem = oo - h * 20;
              attno[(((size_t)b * NHEAD + h) * NTOK + n) * 20 + rem] = v;
            }
          }
        }
      }
    }
  }
}

// ---------------------------------------------------------------------------
// Sampling, two-phase. Block = (b,h) slice x 8x8 token patch.
// Phase 1: 4 lanes/token compute softmax (no max-sub; |logit| small) and all
//   20 weight-quads, packed {4xbf16 w, encoded cell} 16B records in LDS
//   (index p^(tok&3) -> max 2-way bank alias = free).
// Phase 2: 8 dim-lanes/token: per point 1 rec read + 4 gathers + 16 FMA.
// Patch cells staged with zeros outside image -> boundary masking free.
// ---------------------------------------------------------------------------
__global__ __launch_bounds__(256) void sample_kernel(
    const __hip_bfloat16* __restrict__ value, const float* __restrict__ off,
    const float* __restrict__ attn, __hip_bfloat16* __restrict__ outat) {
  const int s = blockIdx.x & 7;  // slice = b*NH+h; low bits spread XCDs
  const int pidx = blockIdx.x >> 3;
  const int PI = pidx % NPATCH, PJ = pidx / NPATCH;
  const int I0 = PI * PTOK, J0 = PJ * PTOK;
  const int b = s >> 2, h = s & 3;

  __shared__ __hip_bfloat16 patch[PDIM * PDIM][CELLPAD];
  __shared__ int4 recs[64][20];
  const __hip_bfloat16* vglob = value + (size_t)s * NTOK * DHEAD;

  // stage patch: 256 cells x 64B, zeros outside image
#pragma unroll
  for (int it = 0; it < 4; ++it) {
    int lin = threadIdx.x + 256 * it;  // 0..1023
    int cell = lin >> 2, part = lin & 3;
    int py = cell >> 4, px = cell & 15;
    int gy = J0 - PHALO + py;
    int gx = I0 - PHALO + px;
    short8v v = (short8v)(short)0;
    if (gy >= 0 && gy < HWDIM && gx >= 0 && gx < HWDIM)
      v = *(const short8v*)(vglob + ((size_t)(gy * HWDIM + gx)) * DHEAD +
                            part * 8);
    *(short8v*)&patch[cell][part * 8] = v;
  }

  // ---- phase 1: weights ----
  {
    const int tok = threadIdx.x >> 2;  // 0..63
    const int pl = threadIdx.x & 3;    // 0..3, 5 points each
    const int li = tok & 7, lj = tok >> 3;
    const int i = I0 + li, j = J0 + lj;
    const bool tv = (i < HWDIM) && (j < HWDIM);
    const int n = tv ? (i * HWDIM + j) : 0;
    const float* obase = off + ((size_t)s * NTOK + n) * (NPNT * 2);
    const float* abase = attn + ((size_t)s * NTOK + n) * NPNT;

    float e[5];
    float psum = 0.f;
#pragma unroll
    for (int k = 0; k < 5; ++k) {
      float lg = tv ? abase[pl * 5 + k] : 0.f;
      e[k] = __expf(lg);
      psum += e[k];
    }
    psum += __shfl_xor(psum, 1);
    psum += __shfl_xor(psum, 2);
    const float inv = tv ? (1.f / psum) : 0.f;
    const float fi = (float)i, fj = (float)j;

#pragma unroll
    for (int k = 0; k < 5; ++k) {
      int p = pl * 5 + k;
      float ox = tv ? obase[2 * p] : 0.f;
      float oy = tv ? obase[2 * p + 1] : 0.f;
      float aw = e[k] * inv;
      float x = fi + ox;   // i-dim
      float y = fj + oy;   // j-dim (multiplies HWDIM)
      float x0f = floorf(x), y0f = floorf(y);
      int ix0 = (int)x0f, iy0 = (int)y0f;
      float wx1 = x - x0f, wy1 = y - y0f;
      float wx0 = 1.f - wx1, wy0 = 1.f - wy1;
      float w00 = aw * wy0 * wx0, w01 = aw * wy0 * wx1;
      float w10 = aw * wy1 * wx0, w11 = aw * wy1 * wx1;
      int ly = iy0 - (J0 - PHALO);
      int lx = ix0 - (I0 - PHALO);
      int z;
      if (ly >= 0 && ly <= PDIM - 2 && lx >= 0 && lx <= PDIM - 2) {
        z = ly * PDIM + lx;
      } else {
        int iyc = min(max(iy0, -1000), 1000) + 1024;
        int ixc = min(max(ix0, -1000), 1000) + 1024;
        z = (1 << 30) | (iyc << 12) | ixc;
      }
      recs[tok][p ^ (tok & 3)] =
          make_int4((int)pack_bf(w00, w01), (int)pack_bf(w10, w11), z, 0);
    }
  }
  __syncthreads();

  // ---- phase 2: gather + accumulate ----
  const int d4 = threadIdx.x & 7;
  const int slot = threadIdx.x >> 3;  // 0..31

  for (int tt = 0; tt < 2; ++tt) {
    const int tok = slot + 32 * tt;
    const int li = tok & 7, lj = tok >> 3;
    const int i = I0 + li, j = J0 + lj;
    if (i >= HWDIM || j >= HWDIM) continue;
    const int n = i * HWDIM + j;
    const int sw = tok & 3;

    float ax = 0.f, ay = 0.f, az = 0.f, aw4 = 0.f;
#pragma unroll
    for (int p = 0; p < NPNT; ++p) {
      int4 rec = recs[tok][p ^ sw];
      float w00 = asf(((unsigned)rec.x) << 16);
      float w01 = asf(((unsigned)rec.x) & 0xFFFF0000u);
      float w10 = asf(((unsigned)rec.y) << 16);
      float w11 = asf(((unsigned)rec.y) & 0xFFFF0000u);
      if (!(rec.z & (1 << 30))) {
        const __hip_bfloat16* pb = &patch[rec.z][d4 * 4];
        short4v g00 = *(const short4v*)pb;
        short4v g01 = *(const short4v*)(pb + CELLPAD);
        short4v g10 = *(const short4v*)(pb + PDIM * CELLPAD);
        short4v g11 = *(const short4v*)(pb + PDIM * CELLPAD + CELLPAD);
        ax += w00 * asf(((unsigned)(unsigned short)g00.x) << 16)
            + w01 * asf(((unsigned)(unsigned short)g01.x) << 16)
            + w10 * asf(((unsigned)(unsigned short)g10.x) << 16)
            + w11 * asf(((unsigned)(unsigned short)g11.x) << 16);
        ay += w00 * asf(((unsigned)(unsigned short)g00.y) << 16)
            + w01 * asf(((unsigned)(unsigned short)g01.y) << 16)
            + w10 * asf(((unsigned)(unsigned short)g10.y) << 16)
            + w11 * asf(((unsigned)(unsigned short)g11.y) << 16);
        az += w00 * asf(((unsigned)(unsigned short)g00.z) << 16)
            + w01 * asf(((unsigned)(unsigned short)g01.z) << 16)
            + w10 * asf(((unsigned)(unsigned short)g10.z) << 16)
            + w11 * asf(((unsigned)(unsigned short)g11.z) << 16);
        aw4 += w00 * asf(((unsigned)(unsigned short)g00.w) << 16)
             + w01 * asf(((unsigned)(unsigned short)g01.w) << 16)
             + w10 * asf(((unsigned)(unsigned short)g10.w) << 16)
             + w11 * asf(((unsigned)(unsigned short)g11.w) << 16);
      } else {
        int iy0 = ((rec.z >> 12) & 0xFFF) - 1024;
        int ix0 = (rec.z & 0xFFF) - 1024;
        float wgt[4] = {w00, w01, w10, w11};
#pragma unroll
        for (int cy = 0; cy < 2; ++cy) {
          int iy = iy0 + cy;
          if (iy < 0 || iy >= HWDIM) continue;
#pragma unroll
          for (int cx = 0; cx < 2; ++cx) {
            int ix = ix0 + cx;
            if (ix < 0 || ix >= HWDIM) continue;
            float w = wgt[cy * 2 + cx];
            short4v g = *(const short4v*)(vglob +
                                          ((size_t)(iy * HWDIM + ix)) * DHEAD +
                                          d4 * 4);
            ax += w * asf(((unsigned)(unsigned short)g.x) << 16);
            ay += w * asf(((unsigned)(unsigned short)g.y) << 16);
            az += w * asf(((unsigned)(unsigned short)g.z) << 16);
            aw4 += w * asf(((unsigned)(unsigned short)g.w) << 16);
          }
        }
      }
    }
    union { short4v v4; __hip_bfloat16 hh[4]; } o;
    o.hh[0] = __float2bfloat16(ax); o.hh[1] = __float2bfloat16(ay);
    o.hh[2] = __float2bfloat16(az); o.hh[3] = __float2bfloat16(aw4);
    *(short4v*)(outat + ((size_t)b * NTOK + n) * CDIM + h * DHEAD + d4 * 4) =
        o.v4;
  }
}

extern "C" void kernel_launch(void* const* d_in, const int* in_sizes, int n_in,
                              void* d_out, int out_size, void* d_ws,
                              size_t ws_size, hipStream_t stream) {
  const float* query = (const float*)d_in[0];
  const float* query_pos = (const float*)d_in[1];
  const float* W_val = (const float*)d_in[2];
  const float* b_val = (const float*)d_in[3];
  const float* W_off = (const float*)d_in[4];
  const float* b_off = (const float*)d_in[5];
  const float* W_attn = (const float*)d_in[6];
  const float* b_attn = (const float*)d_in[7];
  const float* W_out1 = (const float*)d_in[8];
  const float* b_out1 = (const float*)d_in[9];
  const float* W_out2 = (const float*)d_in[10];
  const float* b_out2 = (const float*)d_in[11];
  float* out = (float*)d_out;

  char* ws = (char*)d_ws;
  __hip_bfloat16* value = (__hip_bfloat16*)ws;  // (B*NH,N,32) bf16
  ws += (size_t)MROWS * CDIM * 2;
  float* offb = (float*)ws;                     // (B*NH,N,40) f32
  ws += (size_t)MROWS * 160 * 4;
  float* attnb = (float*)ws;                    // (B*NH,N,20) f32
  ws += (size_t)MROWS * 80 * 4;
  __hip_bfloat16* outat = (__hip_bfloat16*)ws;  // (B,N,C) bf16
  ws += (size_t)MROWS * CDIM * 2;
  float* Wc = (float*)ws; ws += 128 * 128 * 4;
  float* bc = (float*)ws; ws += 128 * 4;
  float* bcat = (float*)ws; ws += OPAD * 4;
  __hip_bfloat16* Wcat = (__hip_bfloat16*)ws; ws += (size_t)OPAD * 128 * 2;
  __hip_bfloat16* Wc_bf = (__hip_bfloat16*)ws;

  fold_kernel<<<128, 128, 0, stream>>>(W_out1, b_out1, W_out2, b_out2, Wc, bc);
  conv_kernel<<<OPAD + 128, 128, 0, stream>>>(W_val, b_val, W_off, b_off,
                                              W_attn, b_attn, Wc, Wcat, bcat,
                                              Wc_bf);

  mfma_proj_kernel<0, 0><<<313, 256, 0, stream>>>(
      query, query_pos, nullptr, Wcat, bcat, value, offb, attnb, nullptr,
      nullptr, MROWS, 6, OCAT);

  sample_kernel<<<8 * NPATCH * NPATCH, 256, 0, stream>>>(value, offb, attnb,
                                                         outat);

  mfma_proj_kernel<1, 1><<<313, 256, 0, stream>>>(
      nullptr, nullptr, outat, Wc_bf, bc, nullptr, nullptr, nullptr, out,
      query, MROWS, 2, 128);
}

// Round 6
// 66.126 us; speedup vs baseline: 1.2482x; 1.2482x over previous
//
#include <hip/hip_runtime.h>
#include <hip/hip_bf16.h>
#include <math.h>

#define NTOK 10000
#define BATCH 2
#define CDIM 128
#define NHEAD 4
#define NPNT 20
#define DHEAD 32
#define HWDIM 100
#define MROWS (BATCH * NTOK)
#define OCAT 368   // 128 value + 160 off + 80 attn
#define OPAD 384   // padded to 64-multiple
#define PTOK 8     // 8x8 tokens per patch
#define PHALO 4    // halo cells each side
#define PDIM 16    // PTOK + 2*PHALO
#define NPATCH 13  // ceil(100/8)
#define CELLPAD 40 // bf16 per cell in LDS (stride 80B: 16B-aligned, 20-bank)

typedef __attribute__((ext_vector_type(8))) short short8v;
typedef __attribute__((ext_vector_type(4))) short short4v;
typedef __attribute__((ext_vector_type(4))) float f32x4;

__device__ __forceinline__ float bfbits(short s) {
  union { unsigned u; float f; } c;
  c.u = ((unsigned)(unsigned short)s) << 16;
  return c.f;
}

// ---------------------------------------------------------------------------
// Fold the two output projections: Wc = W2 @ W1, bc = b2 + W2 @ b1 (fp32)
// ---------------------------------------------------------------------------
__global__ __launch_bounds__(128) void fold_kernel(
    const float* __restrict__ W1, const float* __restrict__ b1,
    const float* __restrict__ W2, const float* __restrict__ b2,
    float* __restrict__ Wc, float* __restrict__ bc) {
  __shared__ float w2row[128];
  __shared__ float red[128];
  int o = blockIdx.x, c = threadIdx.x;
  w2row[c] = W2[o * 128 + c];
  __syncthreads();
  float acc = 0.f;
  for (int k = 0; k < 128; ++k) acc += w2row[k] * W1[k * 128 + c];
  Wc[o * 128 + c] = acc;
  red[c] = w2row[c] * b1[c];
  __syncthreads();
  for (int s = 64; s > 0; s >>= 1) {
    if (c < s) red[c] += red[c + s];
    __syncthreads();
  }
  if (c == 0) bc[o] = b2[o] + red[0];
}

// ---------------------------------------------------------------------------
// Convert weights to bf16: Wcat[384][128], bcat[384]; Wc fp32 -> Wc_bf.
// ---------------------------------------------------------------------------
__global__ __launch_bounds__(128) void conv_kernel(
    const float* __restrict__ W_val, const float* __restrict__ b_val,
    const float* __restrict__ W_off, const float* __restrict__ b_off,
    const float* __restrict__ W_attn, const float* __restrict__ b_attn,
    const float* __restrict__ Wc, __hip_bfloat16* __restrict__ Wcat,
    float* __restrict__ bcat, __hip_bfloat16* __restrict__ Wc_bf) {
  int r = blockIdx.x, c = threadIdx.x;
  if (r < OPAD) {
    float v = 0.f, bv = 0.f;
    if (r < 128) { v = W_val[r * 128 + c]; bv = b_val[r]; }
    else if (r < 288) { v = W_off[(r - 128) * 128 + c]; bv = b_off[r - 128]; }
    else if (r < OCAT) { v = W_attn[(r - 288) * 128 + c]; bv = b_attn[r - 288]; }
    Wcat[(size_t)r * 128 + c] = __float2bfloat16(v);
    if (c == 0) bcat[r] = bv;
  } else {
    int rr = r - OPAD;
    Wc_bf[(size_t)rr * 128 + c] = __float2bfloat16(Wc[rr * 128 + c]);
  }
}

// ---------------------------------------------------------------------------
// MFMA bf16 GEMM. Block: 64 rows x (Otiles x 64) outs starting at
// blockIdx.y*Otiles*64; A staged + fragments hoisted ONCE per block.
// AKIND 0: A = fp32 src+src2 -> bf16.  AKIND 1: A = bf16 src.
// MODE 0: scatter to head-major value(bf16)/off/attn.  MODE 1: fp32 + resid.
// ---------------------------------------------------------------------------
template <int MODE, int AKIND>
__global__ __launch_bounds__(256) void mfma_proj_kernel(
    const float* __restrict__ src_f, const float* __restrict__ src2,
    const __hip_bfloat16* __restrict__ src_b,
    const __hip_bfloat16* __restrict__ Wb, const float* __restrict__ bias,
    __hip_bfloat16* __restrict__ value, float* __restrict__ offo,
    float* __restrict__ attno, float* __restrict__ out,
    const float* __restrict__ resid, int M, int Otiles, int Ototal) {
  __shared__ __hip_bfloat16 qa[64][128];
  __shared__ __hip_bfloat16 wb[64][128];
  const int t = threadIdx.x;
  const int r0 = blockIdx.x * 64;

#pragma unroll
  for (int i = 0; i < 4; ++i) {
    int lin = t + 256 * i;  // 0..1023
    int r = lin >> 4;       // row 0..63
    int g = lin & 15;       // 16B granule
    if (AKIND == 0) {
      int c = g << 3;
      float4 v0 = make_float4(0.f, 0.f, 0.f, 0.f);
      float4 v1 = make_float4(0.f, 0.f, 0.f, 0.f);
      if (r0 + r < M) {
        const float* p = src_f + (size_t)(r0 + r) * CDIM + c;
        v0 = *(const float4*)p;
        v1 = *(const float4*)(p + 4);
        const float* p2 = src2 + (size_t)(r0 + r) * CDIM + c;
        float4 u0 = *(const float4*)p2;
        float4 u1 = *(const float4*)(p2 + 4);
        v0.x += u0.x; v0.y += u0.y; v0.z += u0.z; v0.w += u0.w;
        v1.x += u1.x; v1.y += u1.y; v1.z += u1.z; v1.w += u1.w;
      }
      __hip_bfloat16* dst = &qa[r][(g ^ (r & 7)) << 3];
      dst[0] = __float2bfloat16(v0.x); dst[1] = __float2bfloat16(v0.y);
      dst[2] = __float2bfloat16(v0.z); dst[3] = __float2bfloat16(v0.w);
      dst[4] = __float2bfloat16(v1.x); dst[5] = __float2bfloat16(v1.y);
      dst[6] = __float2bfloat16(v1.z); dst[7] = __float2bfloat16(v1.w);
    } else {
      short8v v = (short8v)(short)0;
      if (r0 + r < M)
        v = *(const short8v*)(src_b + (size_t)(r0 + r) * CDIM + (g << 3));
      *(short8v*)&qa[r][(g ^ (r & 7)) << 3] = v;
    }
  }
  __syncthreads();

  const int wid = t >> 6;
  const int lane = t & 63;
  const int wr = (wid >> 1) * 32;
  const int wc = (wid & 1) * 32;
  const int lrow = lane & 15;
  const int lk = lane >> 4;

  // hoist A fragments (reused across all W tiles of this block)
  short8v afr[4][2];
  {
    int ra0 = wr + lrow, ra1 = wr + 16 + lrow;
#pragma unroll
    for (int kk = 0; kk < 4; ++kk) {
      int gb = kk * 4 + lk;
      afr[kk][0] = *(const short8v*)&qa[ra0][(gb ^ (ra0 & 7)) << 3];
      afr[kk][1] = *(const short8v*)&qa[ra1][(gb ^ (ra1 & 7)) << 3];
    }
  }

  for (int ti = 0; ti < Otiles; ++ti) {
    const int ot = (blockIdx.y * Otiles + ti) * 64;
    __syncthreads();  // previous tile's readers done (and qa stage, 1st iter)
#pragma unroll
    for (int i = 0; i < 4; ++i) {
      int lin = t + 256 * i;
      int r = lin >> 4;
      int g = lin & 15;
      short8v w = *(const short8v*)(Wb + (size_t)(ot + r) * 128 + (g << 3));
      *(short8v*)&wb[r][(g ^ (r & 7)) << 3] = w;
    }
    __syncthreads();

    f32x4 acc[2][2];
#pragma unroll
    for (int mi = 0; mi < 2; ++mi)
#pragma unroll
      for (int ni = 0; ni < 2; ++ni) acc[mi][ni] = (f32x4)(0.f);

#pragma unroll
    for (int kk = 0; kk < 4; ++kk) {
      const int gb = kk * 4 + lk;
      int rb0 = wc + lrow, rb1 = wc + 16 + lrow;
      short8v b0 = *(const short8v*)&wb[rb0][(gb ^ (rb0 & 7)) << 3];
      short8v b1 = *(const short8v*)&wb[rb1][(gb ^ (rb1 & 7)) << 3];
      acc[0][0] = __builtin_amdgcn_mfma_f32_16x16x32_bf16(afr[kk][0], b0, acc[0][0], 0, 0, 0);
      acc[0][1] = __builtin_amdgcn_mfma_f32_16x16x32_bf16(afr[kk][0], b1, acc[0][1], 0, 0, 0);
      acc[1][0] = __builtin_amdgcn_mfma_f32_16x16x32_bf16(afr[kk][1], b0, acc[1][0], 0, 0, 0);
      acc[1][1] = __builtin_amdgcn_mfma_f32_16x16x32_bf16(afr[kk][1], b1, acc[1][1], 0, 0, 0);
    }

    // C/D: col = lane&15, row = (lane>>4)*4 + reg
#pragma unroll
    for (int mi = 0; mi < 2; ++mi) {
#pragma unroll
      for (int ni = 0; ni < 2; ++ni) {
#pragma unroll
        for (int reg = 0; reg < 4; ++reg) {
          int r = r0 + wr + mi * 16 + (lane >> 4) * 4 + reg;
          int o = ot + wc + ni * 16 + (lane & 15);
          if (r >= M || o >= Ototal) continue;
          float v = acc[mi][ni][reg] + bias[o];
          if (MODE == 1) {
            out[(size_t)r * CDIM + o] = v + resid[(size_t)r * CDIM + o];
          } else {
            int b = r >= NTOK ? 1 : 0;
            int n = r - b * NTOK;
            if (o < 128) {
              int h = o >> 5, rem = o & 31;
              value[(((size_t)b * NHEAD + h) * NTOK + n) * 32 + rem] =
                  __float2bfloat16(v);
            } else if (o < 288) {
              int oo = o - 128, h = oo / 40, rem = oo - h * 40;
              offo[(((size_t)b * NHEAD + h) * NTOK + n) * 40 + rem] = v;
            } else {
              int oo = o - 288, h = oo / 20, rem = oo - h * 20;
              attno[(((size_t)b * NHEAD + h) * NTOK + n) * 20 + rem] = v;
            }
          }
        }
      }
    }
  }
}

// ---------------------------------------------------------------------------
// Sampling with LDS patch staging (R4 structure). Block = (b,h) slice x 8x8
// token patch; 16x16 halo'd bf16 cells staged with zeros outside the image.
// 8 lanes/token, 4 dims each. off/attn rows pulled in as float4 (registers),
// softmax without max-subtract (|logit| << 88, mathematically identical).
// Rare out-of-patch samples take a bounds-checked global fallback.
// ---------------------------------------------------------------------------
__global__ __launch_bounds__(256) void sample_kernel(
    const __hip_bfloat16* __restrict__ value, const float* __restrict__ off,
    const float* __restrict__ attn, __hip_bfloat16* __restrict__ outat) {
  const int s = blockIdx.x & 7;  // slice = b*NH+h; low bits spread XCDs
  const int pidx = blockIdx.x >> 3;
  const int PI = pidx % NPATCH, PJ = pidx / NPATCH;
  const int I0 = PI * PTOK, J0 = PJ * PTOK;
  const int b = s >> 2, h = s & 3;

  __shared__ __hip_bfloat16 patch[PDIM * PDIM][CELLPAD];
  const __hip_bfloat16* vglob = value + (size_t)s * NTOK * DHEAD;

  // stage patch: 256 cells x 64B, zeros outside image
#pragma unroll
  for (int it = 0; it < 4; ++it) {
    int lin = threadIdx.x + 256 * it;  // 0..1023
    int cell = lin >> 2, part = lin & 3;
    int py = cell >> 4, px = cell & 15;
    int gy = J0 - PHALO + py;
    int gx = I0 - PHALO + px;
    short8v v = (short8v)(short)0;
    if (gy >= 0 && gy < HWDIM && gx >= 0 && gx < HWDIM)
      v = *(const short8v*)(vglob + ((size_t)(gy * HWDIM + gx)) * DHEAD +
                            part * 8);
    *(short8v*)&patch[cell][part * 8] = v;
  }
  __syncthreads();

  const int d4 = threadIdx.x & 7;
  const int slot = threadIdx.x >> 3;  // 0..31

  for (int tt = 0; tt < 2; ++tt) {
    const int tok = slot + 32 * tt;
    const int li = tok & 7, lj = tok >> 3;
    const int i = I0 + li, j = J0 + lj;
    if (i >= HWDIM || j >= HWDIM) continue;
    const int n = i * HWDIM + j;

    // vectorized pulls of off (40 f32) and attn (20 f32) into registers
    union { float4 v4[10]; float f[40]; } of;
    union { float4 v4[5]; float f[20]; } at;
    {
      const float4* o4 = (const float4*)(off + ((size_t)s * NTOK + n) * 40);
      const float4* a4 = (const float4*)(attn + ((size_t)s * NTOK + n) * 20);
#pragma unroll
      for (int q = 0; q < 10; ++q) of.v4[q] = o4[q];
#pragma unroll
      for (int q = 0; q < 5; ++q) at.v4[q] = a4[q];
    }

    // softmax without max-subtract (logits are small by construction)
    float ssum = 0.f;
#pragma unroll
    for (int p = 0; p < NPNT; ++p) {
      at.f[p] = __expf(at.f[p]);
      ssum += at.f[p];
    }
    const float inv = 1.f / ssum;

    const float fi = (float)i, fj = (float)j;
    float ax = 0.f, ay = 0.f, az = 0.f, aw4 = 0.f;
#pragma unroll
    for (int p = 0; p < NPNT; ++p) {
      float x = fi + of.f[2 * p];      // i-dim coordinate
      float y = fj + of.f[2 * p + 1];  // j-dim coordinate (multiplies HWDIM)
      float aw = at.f[p] * inv;
      float x0f = floorf(x), y0f = floorf(y);
      int ix0 = (int)x0f, iy0 = (int)y0f;
      float wx1 = x - x0f, wy1 = y - y0f;
      float wx0 = 1.f - wx1, wy0 = 1.f - wy1;
      float w00 = aw * wy0 * wx0, w01 = aw * wy0 * wx1;
      float w10 = aw * wy1 * wx0, w11 = aw * wy1 * wx1;
      int ly = iy0 - (J0 - PHALO);
      int lx = ix0 - (I0 - PHALO);
      if (ly >= 0 && ly <= PDIM - 2 && lx >= 0 && lx <= PDIM - 2) {
        const __hip_bfloat16* pb = &patch[ly * PDIM + lx][d4 * 4];
        short4v g00 = *(const short4v*)pb;
        short4v g01 = *(const short4v*)(pb + CELLPAD);
        short4v g10 = *(const short4v*)(pb + PDIM * CELLPAD);
        short4v g11 = *(const short4v*)(pb + PDIM * CELLPAD + CELLPAD);
        ax += w00 * bfbits(g00.x) + w01 * bfbits(g01.x) + w10 * bfbits(g10.x) + w11 * bfbits(g11.x);
        ay += w00 * bfbits(g00.y) + w01 * bfbits(g01.y) + w10 * bfbits(g10.y) + w11 * bfbits(g11.y);
        az += w00 * bfbits(g00.z) + w01 * bfbits(g01.z) + w10 * bfbits(g10.z) + w11 * bfbits(g11.z);
        aw4 += w00 * bfbits(g00.w) + w01 * bfbits(g01.w) + w10 * bfbits(g10.w) + w11 * bfbits(g11.w);
      } else {
        // rare out-of-patch fallback: direct gather with bounds checks
        float wgt[4] = {w00, w01, w10, w11};
#pragma unroll
        for (int cy = 0; cy < 2; ++cy) {
          int iy = iy0 + cy;
          if (iy < 0 || iy >= HWDIM) continue;
#pragma unroll
          for (int cx = 0; cx < 2; ++cx) {
            int ix = ix0 + cx;
            if (ix < 0 || ix >= HWDIM) continue;
            float w = wgt[cy * 2 + cx];
            short4v g = *(const short4v*)(vglob +
                                          ((size_t)(iy * HWDIM + ix)) * DHEAD +
                                          d4 * 4);
            ax += w * bfbits(g.x); ay += w * bfbits(g.y);
            az += w * bfbits(g.z); aw4 += w * bfbits(g.w);
          }
        }
      }
    }
    union { short4v v4; __hip_bfloat16 hh[4]; } o;
    o.hh[0] = __float2bfloat16(ax); o.hh[1] = __float2bfloat16(ay);
    o.hh[2] = __float2bfloat16(az); o.hh[3] = __float2bfloat16(aw4);
    *(short4v*)(outat + ((size_t)b * NTOK + n) * CDIM + h * DHEAD + d4 * 4) =
        o.v4;
  }
}

extern "C" void kernel_launch(void* const* d_in, const int* in_sizes, int n_in,
                              void* d_out, int out_size, void* d_ws,
                              size_t ws_size, hipStream_t stream) {
  const float* query = (const float*)d_in[0];
  const float* query_pos = (const float*)d_in[1];
  const float* W_val = (const float*)d_in[2];
  const float* b_val = (const float*)d_in[3];
  const float* W_off = (const float*)d_in[4];
  const float* b_off = (const float*)d_in[5];
  const float* W_attn = (const float*)d_in[6];
  const float* b_attn = (const float*)d_in[7];
  const float* W_out1 = (const float*)d_in[8];
  const float* b_out1 = (const float*)d_in[9];
  const float* W_out2 = (const float*)d_in[10];
  const float* b_out2 = (const float*)d_in[11];
  float* out = (float*)d_out;

  char* ws = (char*)d_ws;
  __hip_bfloat16* value = (__hip_bfloat16*)ws;  // (B*NH,N,32) bf16
  ws += (size_t)MROWS * CDIM * 2;
  float* offb = (float*)ws;                     // (B*NH,N,40) f32
  ws += (size_t)MROWS * 160 * 4;
  float* attnb = (float*)ws;                    // (B*NH,N,20) f32
  ws += (size_t)MROWS * 80 * 4;
  __hip_bfloat16* outat = (__hip_bfloat16*)ws;  // (B,N,C) bf16
  ws += (size_t)MROWS * CDIM * 2;
  float* Wc = (float*)ws; ws += 128 * 128 * 4;
  float* bc = (float*)ws; ws += 128 * 4;
  float* bcat = (float*)ws; ws += OPAD * 4;
  __hip_bfloat16* Wcat = (__hip_bfloat16*)ws; ws += (size_t)OPAD * 128 * 2;
  __hip_bfloat16* Wc_bf = (__hip_bfloat16*)ws;

  fold_kernel<<<128, 128, 0, stream>>>(W_out1, b_out1, W_out2, b_out2, Wc, bc);
  conv_kernel<<<OPAD + 128, 128, 0, stream>>>(W_val, b_val, W_off, b_off,
                                              W_attn, b_attn, Wc, Wcat, bcat,
                                              Wc_bf);

  // proj1: grid (313,2), 3 internal W-tiles each -> A read twice, no tail
  mfma_proj_kernel<0, 0><<<dim3(313, 2), 256, 0, stream>>>(
      query, query_pos, nullptr, Wcat, bcat, value, offb, attnb, nullptr,
      nullptr, MROWS, 3, OCAT);

  sample_kernel<<<8 * NPATCH * NPATCH, 256, 0, stream>>>(value, offb, attnb,
                                                         outat);

  // proj2: grid (313,2), 1 tile each
  mfma_proj_kernel<1, 1><<<dim3(313, 2), 256, 0, stream>>>(
      nullptr, nullptr, outat, Wc_bf, bc, nullptr, nullptr, nullptr, out,
      query, MROWS, 1, 128);
}

// Round 7
// 60.818 us; speedup vs baseline: 1.3571x; 1.0873x over previous
//
#include <hip/hip_runtime.h>
#include <hip/hip_bf16.h>
#include <math.h>

#define NTOK 10000
#define BATCH 2
#define CDIM 128
#define NHEAD 4
#define NPNT 20
#define DHEAD 32
#define HWDIM 100
#define MROWS (BATCH * NTOK)
#define OCAT 368   // 128 value + 160 off + 80 attn
#define OPAD 384   // padded to 64-multiple
#define PTOK 8     // 8x8 tokens per patch
#define PHALO 4    // halo cells each side
#define PDIM 16    // PTOK + 2*PHALO
#define NPATCH 13  // ceil(100/8)
#define CELLPAD 40 // bf16 per cell in LDS (stride 80B: 16B-aligned)

typedef __attribute__((ext_vector_type(8))) short short8v;
typedef __attribute__((ext_vector_type(4))) short short4v;
typedef __attribute__((ext_vector_type(4))) float f32x4;

__device__ __forceinline__ float asf(unsigned u) {
  union { unsigned u; float f; } c; c.u = u; return c.f;
}

// unpack 8 bf16 (16B) and accumulate w * g into two f32x4 accumulators
__device__ __forceinline__ void acc_cell(const __hip_bfloat16* p, float w,
                                         f32x4& a0, f32x4& a1) {
  int4 u = *(const int4*)p;
  f32x4 g0, g1;
  g0.x = asf(((unsigned)u.x) << 16); g0.y = asf(((unsigned)u.x) & 0xFFFF0000u);
  g0.z = asf(((unsigned)u.y) << 16); g0.w = asf(((unsigned)u.y) & 0xFFFF0000u);
  g1.x = asf(((unsigned)u.z) << 16); g1.y = asf(((unsigned)u.z) & 0xFFFF0000u);
  g1.z = asf(((unsigned)u.w) << 16); g1.w = asf(((unsigned)u.w) & 0xFFFF0000u);
  a0 += g0 * w;
  a1 += g1 * w;
}

// ---------------------------------------------------------------------------
// prep: blocks [0,OPAD): Wcat[r][128] = bf16 of {W_val,W_off,W_attn,pad},
// bcat[r]; blocks [OPAD,OPAD+128): fold Wc = W2@W1 row -> Wc_bf, bc.
// ---------------------------------------------------------------------------
__global__ __launch_bounds__(128) void prep_kernel(
    const float* __restrict__ W_val, const float* __restrict__ b_val,
    const float* __restrict__ W_off, const float* __restrict__ b_off,
    const float* __restrict__ W_attn, const float* __restrict__ b_attn,
    const float* __restrict__ W1, const float* __restrict__ b1,
    const float* __restrict__ W2, const float* __restrict__ b2,
    __hip_bfloat16* __restrict__ Wcat, float* __restrict__ bcat,
    __hip_bfloat16* __restrict__ Wc_bf, float* __restrict__ bc) {
  __shared__ float w2row[128];
  __shared__ float red[128];
  const int blk = blockIdx.x, c = threadIdx.x;
  if (blk < OPAD) {
    float v = 0.f, bv = 0.f;
    if (blk < 128) { v = W_val[blk * 128 + c]; bv = b_val[blk]; }
    else if (blk < 288) { v = W_off[(blk - 128) * 128 + c]; bv = b_off[blk - 128]; }
    else if (blk < OCAT) { v = W_attn[(blk - 288) * 128 + c]; bv = b_attn[blk - 288]; }
    Wcat[(size_t)blk * 128 + c] = __float2bfloat16(v);
    if (c == 0) bcat[blk] = bv;
  } else {
    const int o = blk - OPAD;  // 0..127
    w2row[c] = W2[o * 128 + c];
    __syncthreads();
    float acc = 0.f;
    for (int k = 0; k < 128; ++k) acc += w2row[k] * W1[k * 128 + c];
    Wc_bf[(size_t)o * 128 + c] = __float2bfloat16(acc);
    red[c] = w2row[c] * b1[c];
    __syncthreads();
    for (int s = 64; s > 0; s >>= 1) {
      if (c < s) red[c] += red[c + s];
      __syncthreads();
    }
    if (c == 0) bc[o] = b2[o] + red[0];
  }
}

// ---------------------------------------------------------------------------
// MFMA bf16 GEMM. Block: 64 rows x (Otiles x 64) outs starting at
// blockIdx.y*Otiles*64; A staged + fragments hoisted ONCE per block.
// AKIND 0: A = fp32 src+src2 -> bf16.  AKIND 1: A = bf16 src.
// MODE 0: scatter to head-major value(bf16)/off/attn.  MODE 1: fp32 + resid.
// ---------------------------------------------------------------------------
template <int MODE, int AKIND>
__global__ __launch_bounds__(256) void mfma_proj_kernel(
    const float* __restrict__ src_f, const float* __restrict__ src2,
    const __hip_bfloat16* __restrict__ src_b,
    const __hip_bfloat16* __restrict__ Wb, const float* __restrict__ bias,
    __hip_bfloat16* __restrict__ value, float* __restrict__ offo,
    float* __restrict__ attno, float* __restrict__ out,
    const float* __restrict__ resid, int M, int Otiles, int Ototal) {
  __shared__ __hip_bfloat16 qa[64][128];
  __shared__ __hip_bfloat16 wb[64][128];
  const int t = threadIdx.x;
  const int r0 = blockIdx.x * 64;

#pragma unroll
  for (int i = 0; i < 4; ++i) {
    int lin = t + 256 * i;  // 0..1023
    int r = lin >> 4;       // row 0..63
    int g = lin & 15;       // 16B granule
    if (AKIND == 0) {
      int c = g << 3;
      float4 v0 = make_float4(0.f, 0.f, 0.f, 0.f);
      float4 v1 = make_float4(0.f, 0.f, 0.f, 0.f);
      if (r0 + r < M) {
        const float* p = src_f + (size_t)(r0 + r) * CDIM + c;
        v0 = *(const float4*)p;
        v1 = *(const float4*)(p + 4);
        const float* p2 = src2 + (size_t)(r0 + r) * CDIM + c;
        float4 u0 = *(const float4*)p2;
        float4 u1 = *(const float4*)(p2 + 4);
        v0.x += u0.x; v0.y += u0.y; v0.z += u0.z; v0.w += u0.w;
        v1.x += u1.x; v1.y += u1.y; v1.z += u1.z; v1.w += u1.w;
      }
      __hip_bfloat16* dst = &qa[r][(g ^ (r & 7)) << 3];
      dst[0] = __float2bfloat16(v0.x); dst[1] = __float2bfloat16(v0.y);
      dst[2] = __float2bfloat16(v0.z); dst[3] = __float2bfloat16(v0.w);
      dst[4] = __float2bfloat16(v1.x); dst[5] = __float2bfloat16(v1.y);
      dst[6] = __float2bfloat16(v1.z); dst[7] = __float2bfloat16(v1.w);
    } else {
      short8v v = (short8v)(short)0;
      if (r0 + r < M)
        v = *(const short8v*)(src_b + (size_t)(r0 + r) * CDIM + (g << 3));
      *(short8v*)&qa[r][(g ^ (r & 7)) << 3] = v;
    }
  }
  __syncthreads();

  const int wid = t >> 6;
  const int lane = t & 63;
  const int wr = (wid >> 1) * 32;
  const int wc = (wid & 1) * 32;
  const int lrow = lane & 15;
  const int lk = lane >> 4;

  short8v afr[4][2];
  {
    int ra0 = wr + lrow, ra1 = wr + 16 + lrow;
#pragma unroll
    for (int kk = 0; kk < 4; ++kk) {
      int gb = kk * 4 + lk;
      afr[kk][0] = *(const short8v*)&qa[ra0][(gb ^ (ra0 & 7)) << 3];
      afr[kk][1] = *(const short8v*)&qa[ra1][(gb ^ (ra1 & 7)) << 3];
    }
  }

  for (int ti = 0; ti < Otiles; ++ti) {
    const int ot = (blockIdx.y * Otiles + ti) * 64;
    __syncthreads();
#pragma unroll
    for (int i = 0; i < 4; ++i) {
      int lin = t + 256 * i;
      int r = lin >> 4;
      int g = lin & 15;
      short8v w = *(const short8v*)(Wb + (size_t)(ot + r) * 128 + (g << 3));
      *(short8v*)&wb[r][(g ^ (r & 7)) << 3] = w;
    }
    __syncthreads();

    f32x4 acc[2][2];
#pragma unroll
    for (int mi = 0; mi < 2; ++mi)
#pragma unroll
      for (int ni = 0; ni < 2; ++ni) acc[mi][ni] = (f32x4)(0.f);

#pragma unroll
    for (int kk = 0; kk < 4; ++kk) {
      const int gb = kk * 4 + lk;
      int rb0 = wc + lrow, rb1 = wc + 16 + lrow;
      short8v b0 = *(const short8v*)&wb[rb0][(gb ^ (rb0 & 7)) << 3];
      short8v b1 = *(const short8v*)&wb[rb1][(gb ^ (rb1 & 7)) << 3];
      acc[0][0] = __builtin_amdgcn_mfma_f32_16x16x32_bf16(afr[kk][0], b0, acc[0][0], 0, 0, 0);
      acc[0][1] = __builtin_amdgcn_mfma_f32_16x16x32_bf16(afr[kk][0], b1, acc[0][1], 0, 0, 0);
      acc[1][0] = __builtin_amdgcn_mfma_f32_16x16x32_bf16(afr[kk][1], b0, acc[1][0], 0, 0, 0);
      acc[1][1] = __builtin_amdgcn_mfma_f32_16x16x32_bf16(afr[kk][1], b1, acc[1][1], 0, 0, 0);
    }

    // C/D: col = lane&15, row = (lane>>4)*4 + reg
#pragma unroll
    for (int mi = 0; mi < 2; ++mi) {
#pragma unroll
      for (int ni = 0; ni < 2; ++ni) {
#pragma unroll
        for (int reg = 0; reg < 4; ++reg) {
          int r = r0 + wr + mi * 16 + (lane >> 4) * 4 + reg;
          int o = ot + wc + ni * 16 + (lane & 15);
          if (r >= M || o >= Ototal) continue;
          float v = acc[mi][ni][reg] + bias[o];
          if (MODE == 1) {
            out[(size_t)r * CDIM + o] = v + resid[(size_t)r * CDIM + o];
          } else {
            int b = r >= NTOK ? 1 : 0;
            int n = r - b * NTOK;
            if (o < 128) {
              int h = o >> 5, rem = o & 31;
              value[(((size_t)b * NHEAD + h) * NTOK + n) * 32 + rem] =
                  __float2bfloat16(v);
            } else if (o < 288) {
              int oo = o - 128, h = oo / 40, rem = oo - h * 40;
              offo[(((size_t)b * NHEAD + h) * NTOK + n) * 40 + rem] = v;
            } else {
              int oo = o - 288, h = oo / 20, rem = oo - h * 20;
              attno[(((size_t)b * NHEAD + h) * NTOK + n) * 20 + rem] = v;
            }
          }
        }
      }
    }
  }
}

// ---------------------------------------------------------------------------
// Sampling: 4 lanes/token, 8 dims/lane. Block = (b,h) slice x 8x8 token
// patch; 16x16 halo'd bf16 cells staged (zeros outside image). Per corner:
// one ds_read_b128 + u32 unpack + f32x4 accumulate (v_pk_fma). Softmax
// normalization deferred to the final store (linearity). Rare out-of-patch
// samples take a bounds-checked global fallback.
// ---------------------------------------------------------------------------
__global__ __launch_bounds__(256) void sample_kernel(
    const __hip_bfloat16* __restrict__ value, const float* __restrict__ off,
    const float* __restrict__ attn, __hip_bfloat16* __restrict__ outat) {
  const int s = blockIdx.x & 7;  // slice = b*NH+h; low bits spread XCDs
  const int pidx = blockIdx.x >> 3;
  const int PI = pidx % NPATCH, PJ = pidx / NPATCH;
  const int I0 = PI * PTOK, J0 = PJ * PTOK;
  const int b = s >> 2, h = s & 3;

  __shared__ __hip_bfloat16 patch[PDIM * PDIM][CELLPAD];
  const __hip_bfloat16* vglob = value + (size_t)s * NTOK * DHEAD;

  // stage patch: 256 cells x 64B, zeros outside image
#pragma unroll
  for (int it = 0; it < 4; ++it) {
    int lin = threadIdx.x + 256 * it;  // 0..1023
    int cell = lin >> 2, part = lin & 3;
    int py = cell >> 4, px = cell & 15;
    int gy = J0 - PHALO + py;
    int gx = I0 - PHALO + px;
    short8v v = (short8v)(short)0;
    if (gy >= 0 && gy < HWDIM && gx >= 0 && gx < HWDIM)
      v = *(const short8v*)(vglob + ((size_t)(gy * HWDIM + gx)) * DHEAD +
                            part * 8);
    *(short8v*)&patch[cell][part * 8] = v;
  }
  __syncthreads();

  const int dl = threadIdx.x & 3;    // dim group: 8 dims at dl*8
  const int tok = threadIdx.x >> 2;  // 0..63
  const int li = tok & 7, lj = tok >> 3;
  const int i = I0 + li, j = J0 + lj;
  if (i >= HWDIM || j >= HWDIM) return;
  const int n = i * HWDIM + j;

  // vectorized pulls of off (40 f32) and attn (20 f32) into registers
  union { float4 v4[10]; float f[40]; } of;
  union { float4 v4[5]; float f[20]; } at;
  {
    const float4* o4 = (const float4*)(off + ((size_t)s * NTOK + n) * 40);
    const float4* a4 = (const float4*)(attn + ((size_t)s * NTOK + n) * 20);
#pragma unroll
    for (int q = 0; q < 10; ++q) of.v4[q] = o4[q];
#pragma unroll
    for (int q = 0; q < 5; ++q) at.v4[q] = a4[q];
  }

  // softmax exp (no max-sub: logits are small by construction); norm deferred
  float ssum = 0.f;
#pragma unroll
  for (int p = 0; p < NPNT; ++p) {
    at.f[p] = __expf(at.f[p]);
    ssum += at.f[p];
  }
  const float inv = 1.f / ssum;

  const float fi = (float)i, fj = (float)j;
  f32x4 a0 = (f32x4)(0.f), a1 = (f32x4)(0.f);
#pragma unroll
  for (int p = 0; p < NPNT; ++p) {
    float x = fi + of.f[2 * p];      // i-dim coordinate
    float y = fj + of.f[2 * p + 1];  // j-dim coordinate (multiplies HWDIM)
    float aw = at.f[p];              // un-normalized weight
    float x0f = floorf(x), y0f = floorf(y);
    int ix0 = (int)x0f, iy0 = (int)y0f;
    float wx1 = x - x0f, wy1 = y - y0f;
    float wx0 = 1.f - wx1, wy0 = 1.f - wy1;
    float wya = aw * wy0, wyb = aw * wy1;
    float w00 = wya * wx0, w01 = wya * wx1;
    float w10 = wyb * wx0, w11 = wyb * wx1;
    int ly = iy0 - (J0 - PHALO);
    int lx = ix0 - (I0 - PHALO);
    if (ly >= 0 && ly <= PDIM - 2 && lx >= 0 && lx <= PDIM - 2) {
      const __hip_bfloat16* pb = &patch[ly * PDIM + lx][dl * 8];
      acc_cell(pb, w00, a0, a1);
      acc_cell(pb + CELLPAD, w01, a0, a1);
      acc_cell(pb + PDIM * CELLPAD, w10, a0, a1);
      acc_cell(pb + PDIM * CELLPAD + CELLPAD, w11, a0, a1);
    } else {
      // rare out-of-patch fallback: direct gather with bounds checks
      float wgt[4] = {w00, w01, w10, w11};
#pragma unroll
      for (int cy = 0; cy < 2; ++cy) {
        int iy = iy0 + cy;
        if (iy < 0 || iy >= HWDIM) continue;
#pragma unroll
        for (int cx = 0; cx < 2; ++cx) {
          int ix = ix0 + cx;
          if (ix < 0 || ix >= HWDIM) continue;
          acc_cell(vglob + ((size_t)(iy * HWDIM + ix)) * DHEAD + dl * 8,
                   wgt[cy * 2 + cx], a0, a1);
        }
      }
    }
  }

  union { short8v v8; __hip_bfloat16 hh[8]; } o;
#pragma unroll
  for (int k = 0; k < 4; ++k) {
    o.hh[k] = __float2bfloat16(a0[k] * inv);
    o.hh[4 + k] = __float2bfloat16(a1[k] * inv);
  }
  *(short8v*)(outat + ((size_t)b * NTOK + n) * CDIM + h * DHEAD + dl * 8) =
      o.v8;
}

extern "C" void kernel_launch(void* const* d_in, const int* in_sizes, int n_in,
                              void* d_out, int out_size, void* d_ws,
                              size_t ws_size, hipStream_t stream) {
  const float* query = (const float*)d_in[0];
  const float* query_pos = (const float*)d_in[1];
  const float* W_val = (const float*)d_in[2];
  const float* b_val = (const float*)d_in[3];
  const float* W_off = (const float*)d_in[4];
  const float* b_off = (const float*)d_in[5];
  const float* W_attn = (const float*)d_in[6];
  const float* b_attn = (const float*)d_in[7];
  const float* W_out1 = (const float*)d_in[8];
  const float* b_out1 = (const float*)d_in[9];
  const float* W_out2 = (const float*)d_in[10];
  const float* b_out2 = (const float*)d_in[11];
  float* out = (float*)d_out;

  char* ws = (char*)d_ws;
  __hip_bfloat16* value = (__hip_bfloat16*)ws;  // (B*NH,N,32) bf16
  ws += (size_t)MROWS * CDIM * 2;
  float* offb = (float*)ws;                     // (B*NH,N,40) f32
  ws += (size_t)MROWS * 160 * 4;
  float* attnb = (float*)ws;                    // (B*NH,N,20) f32
  ws += (size_t)MROWS * 80 * 4;
  __hip_bfloat16* outat = (__hip_bfloat16*)ws;  // (B,N,C) bf16
  ws += (size_t)MROWS * CDIM * 2;
  float* bc = (float*)ws; ws += 128 * 4;
  float* bcat = (float*)ws; ws += OPAD * 4;
  __hip_bfloat16* Wcat = (__hip_bfloat16*)ws; ws += (size_t)OPAD * 128 * 2;
  __hip_bfloat16* Wc_bf = (__hip_bfloat16*)ws;

  prep_kernel<<<OPAD + 128, 128, 0, stream>>>(
      W_val, b_val, W_off, b_off, W_attn, b_attn, W_out1, b_out1, W_out2,
      b_out2, Wcat, bcat, Wc_bf, bc);

  // proj1: grid (313,2), 3 internal W-tiles each
  mfma_proj_kernel<0, 0><<<dim3(313, 2), 256, 0, stream>>>(
      query, query_pos, nullptr, Wcat, bcat, value, offb, attnb, nullptr,
      nullptr, MROWS, 3, OCAT);

  sample_kernel<<<8 * NPATCH * NPATCH, 256, 0, stream>>>(value, offb, attnb,
                                                         outat);

  // proj2: grid (313,2), 1 tile each
  mfma_proj_kernel<1, 1><<<dim3(313, 2), 256, 0, stream>>>(
      nullptr, nullptr, outat, Wc_bf, bc, nullptr, nullptr, nullptr, out,
      query, MROWS, 1, 128);
}

// Round 8
// 60.732 us; speedup vs baseline: 1.3590x; 1.0014x over previous
//
#include <hip/hip_runtime.h>
#include <hip/hip_bf16.h>
#include <math.h>

#define NTOK 10000
#define BATCH 2
#define CDIM 128
#define NHEAD 4
#define NPNT 20
#define DHEAD 32
#define HWDIM 100
#define MROWS (BATCH * NTOK)
#define OCAT 368   // 128 value + 160 off + 80 attn
#define OPAD 384   // padded to 64-multiple
#define PTOK 8     // 8x8 tokens per patch
#define PHALO 4    // halo cells each side
#define PDIM 16    // PTOK + 2*PHALO
#define NPATCH 13  // ceil(100/8)
#define CELLPAD 40 // bf16 per cell in LDS (stride 80B: 16B-aligned)

typedef __attribute__((ext_vector_type(8))) short short8v;
typedef __attribute__((ext_vector_type(4))) short short4v;
typedef __attribute__((ext_vector_type(4))) float f32x4;

__device__ __forceinline__ float asf(unsigned u) {
  union { unsigned u; float f; } c; c.u = u; return c.f;
}

// unpack 8 bf16 (16B) and accumulate w * g into two f32x4 accumulators
__device__ __forceinline__ void acc_cell(const __hip_bfloat16* p, float w,
                                         f32x4& a0, f32x4& a1) {
  int4 u = *(const int4*)p;
  f32x4 g0, g1;
  g0.x = asf(((unsigned)u.x) << 16); g0.y = asf(((unsigned)u.x) & 0xFFFF0000u);
  g0.z = asf(((unsigned)u.y) << 16); g0.w = asf(((unsigned)u.y) & 0xFFFF0000u);
  g1.x = asf(((unsigned)u.z) << 16); g1.y = asf(((unsigned)u.z) & 0xFFFF0000u);
  g1.z = asf(((unsigned)u.w) << 16); g1.w = asf(((unsigned)u.w) & 0xFFFF0000u);
  a0 += g0 * w;
  a1 += g1 * w;
}

// ---------------------------------------------------------------------------
// prep: blocks [0,OPAD): Wcat[r][128] = bf16 of {W_val,W_off,W_attn,pad},
// bcat[r]; blocks [OPAD,OPAD+128): fold Wc = W2@W1 row -> Wc_bf, bc.
// ---------------------------------------------------------------------------
__global__ __launch_bounds__(128) void prep_kernel(
    const float* __restrict__ W_val, const float* __restrict__ b_val,
    const float* __restrict__ W_off, const float* __restrict__ b_off,
    const float* __restrict__ W_attn, const float* __restrict__ b_attn,
    const float* __restrict__ W1, const float* __restrict__ b1,
    const float* __restrict__ W2, const float* __restrict__ b2,
    __hip_bfloat16* __restrict__ Wcat, float* __restrict__ bcat,
    __hip_bfloat16* __restrict__ Wc_bf, float* __restrict__ bc) {
  __shared__ float w2row[128];
  __shared__ float red[128];
  const int blk = blockIdx.x, c = threadIdx.x;
  if (blk < OPAD) {
    float v = 0.f, bv = 0.f;
    if (blk < 128) { v = W_val[blk * 128 + c]; bv = b_val[blk]; }
    else if (blk < 288) { v = W_off[(blk - 128) * 128 + c]; bv = b_off[blk - 128]; }
    else if (blk < OCAT) { v = W_attn[(blk - 288) * 128 + c]; bv = b_attn[blk - 288]; }
    Wcat[(size_t)blk * 128 + c] = __float2bfloat16(v);
    if (c == 0) bcat[blk] = bv;
  } else {
    const int o = blk - OPAD;  // 0..127
    w2row[c] = W2[o * 128 + c];
    __syncthreads();
    float acc = 0.f;
    for (int k = 0; k < 128; ++k) acc += w2row[k] * W1[k * 128 + c];
    Wc_bf[(size_t)o * 128 + c] = __float2bfloat16(acc);
    red[c] = w2row[c] * b1[c];
    __syncthreads();
    for (int s = 64; s > 0; s >>= 1) {
      if (c < s) red[c] += red[c + s];
      __syncthreads();
    }
    if (c == 0) bc[o] = b2[o] + red[0];
  }
}

// ---------------------------------------------------------------------------
// MFMA bf16 GEMM. Block: 64 rows x (Otiles x 64) outs starting at
// blockIdx.y*Otiles*64; A staged + fragments hoisted ONCE per block.
// AKIND 0: A = fp32 src+src2 -> bf16.  AKIND 1: A = bf16 src.
// MODE 0: scatter to head-major value(bf16)/off(bf16)/attn(f32).
// MODE 1: row-major fp32 + residual.
// ---------------------------------------------------------------------------
template <int MODE, int AKIND>
__global__ __launch_bounds__(256) void mfma_proj_kernel(
    const float* __restrict__ src_f, const float* __restrict__ src2,
    const __hip_bfloat16* __restrict__ src_b,
    const __hip_bfloat16* __restrict__ Wb, const float* __restrict__ bias,
    __hip_bfloat16* __restrict__ value, __hip_bfloat16* __restrict__ offo,
    float* __restrict__ attno, float* __restrict__ out,
    const float* __restrict__ resid, int M, int Otiles, int Ototal) {
  __shared__ __hip_bfloat16 qa[64][128];
  __shared__ __hip_bfloat16 wb[64][128];
  const int t = threadIdx.x;
  const int r0 = blockIdx.x * 64;

#pragma unroll
  for (int i = 0; i < 4; ++i) {
    int lin = t + 256 * i;  // 0..1023
    int r = lin >> 4;       // row 0..63
    int g = lin & 15;       // 16B granule
    if (AKIND == 0) {
      int c = g << 3;
      float4 v0 = make_float4(0.f, 0.f, 0.f, 0.f);
      float4 v1 = make_float4(0.f, 0.f, 0.f, 0.f);
      if (r0 + r < M) {
        const float* p = src_f + (size_t)(r0 + r) * CDIM + c;
        v0 = *(const float4*)p;
        v1 = *(const float4*)(p + 4);
        const float* p2 = src2 + (size_t)(r0 + r) * CDIM + c;
        float4 u0 = *(const float4*)p2;
        float4 u1 = *(const float4*)(p2 + 4);
        v0.x += u0.x; v0.y += u0.y; v0.z += u0.z; v0.w += u0.w;
        v1.x += u1.x; v1.y += u1.y; v1.z += u1.z; v1.w += u1.w;
      }
      __hip_bfloat16* dst = &qa[r][(g ^ (r & 7)) << 3];
      dst[0] = __float2bfloat16(v0.x); dst[1] = __float2bfloat16(v0.y);
      dst[2] = __float2bfloat16(v0.z); dst[3] = __float2bfloat16(v0.w);
      dst[4] = __float2bfloat16(v1.x); dst[5] = __float2bfloat16(v1.y);
      dst[6] = __float2bfloat16(v1.z); dst[7] = __float2bfloat16(v1.w);
    } else {
      short8v v = (short8v)(short)0;
      if (r0 + r < M)
        v = *(const short8v*)(src_b + (size_t)(r0 + r) * CDIM + (g << 3));
      *(short8v*)&qa[r][(g ^ (r & 7)) << 3] = v;
    }
  }
  __syncthreads();

  const int wid = t >> 6;
  const int lane = t & 63;
  const int wr = (wid >> 1) * 32;
  const int wc = (wid & 1) * 32;
  const int lrow = lane & 15;
  const int lk = lane >> 4;

  short8v afr[4][2];
  {
    int ra0 = wr + lrow, ra1 = wr + 16 + lrow;
#pragma unroll
    for (int kk = 0; kk < 4; ++kk) {
      int gb = kk * 4 + lk;
      afr[kk][0] = *(const short8v*)&qa[ra0][(gb ^ (ra0 & 7)) << 3];
      afr[kk][1] = *(const short8v*)&qa[ra1][(gb ^ (ra1 & 7)) << 3];
    }
  }

  for (int ti = 0; ti < Otiles; ++ti) {
    const int ot = (blockIdx.y * Otiles + ti) * 64;
    __syncthreads();
#pragma unroll
    for (int i = 0; i < 4; ++i) {
      int lin = t + 256 * i;
      int r = lin >> 4;
      int g = lin & 15;
      short8v w = *(const short8v*)(Wb + (size_t)(ot + r) * 128 + (g << 3));
      *(short8v*)&wb[r][(g ^ (r & 7)) << 3] = w;
    }
    __syncthreads();

    f32x4 acc[2][2];
#pragma unroll
    for (int mi = 0; mi < 2; ++mi)
#pragma unroll
      for (int ni = 0; ni < 2; ++ni) acc[mi][ni] = (f32x4)(0.f);

#pragma unroll
    for (int kk = 0; kk < 4; ++kk) {
      const int gb = kk * 4 + lk;
      int rb0 = wc + lrow, rb1 = wc + 16 + lrow;
      short8v b0 = *(const short8v*)&wb[rb0][(gb ^ (rb0 & 7)) << 3];
      short8v b1 = *(const short8v*)&wb[rb1][(gb ^ (rb1 & 7)) << 3];
      acc[0][0] = __builtin_amdgcn_mfma_f32_16x16x32_bf16(afr[kk][0], b0, acc[0][0], 0, 0, 0);
      acc[0][1] = __builtin_amdgcn_mfma_f32_16x16x32_bf16(afr[kk][0], b1, acc[0][1], 0, 0, 0);
      acc[1][0] = __builtin_amdgcn_mfma_f32_16x16x32_bf16(afr[kk][1], b0, acc[1][0], 0, 0, 0);
      acc[1][1] = __builtin_amdgcn_mfma_f32_16x16x32_bf16(afr[kk][1], b1, acc[1][1], 0, 0, 0);
    }

    // C/D: col = lane&15, row = (lane>>4)*4 + reg
#pragma unroll
    for (int mi = 0; mi < 2; ++mi) {
#pragma unroll
      for (int ni = 0; ni < 2; ++ni) {
#pragma unroll
        for (int reg = 0; reg < 4; ++reg) {
          int r = r0 + wr + mi * 16 + (lane >> 4) * 4 + reg;
          int o = ot + wc + ni * 16 + (lane & 15);
          if (r >= M || o >= Ototal) continue;
          float v = acc[mi][ni][reg] + bias[o];
          if (MODE == 1) {
            out[(size_t)r * CDIM + o] = v + resid[(size_t)r * CDIM + o];
          } else {
            int b = r >= NTOK ? 1 : 0;
            int n = r - b * NTOK;
            if (o < 128) {
              int h = o >> 5, rem = o & 31;
              value[(((size_t)b * NHEAD + h) * NTOK + n) * 32 + rem] =
                  __float2bfloat16(v);
            } else if (o < 288) {
              int oo = o - 128, h = oo / 40, rem = oo - h * 40;
              offo[(((size_t)b * NHEAD + h) * NTOK + n) * 40 + rem] =
                  __float2bfloat16(v);
            } else {
              int oo = o - 288, h = oo / 20, rem = oo - h * 20;
              attno[(((size_t)b * NHEAD + h) * NTOK + n) * 20 + rem] = v;
            }
          }
        }
      }
    }
  }
}

// ---------------------------------------------------------------------------
// Sampling: 4 lanes/token, 8 dims/lane. Block = (b,h) slice x 8x8 token
// patch; 16x16 halo'd bf16 cells staged (zeros outside image). Per corner:
// one ds_read_b128 + u32 unpack + f32x4 accumulate. FOUR independent
// accumulator pairs (one per bilinear corner) break the FMA dependence
// chain; offsets arrive as packed bf16 pairs (one u32 per point). Softmax
// normalization deferred to the final store.
// ---------------------------------------------------------------------------
__global__ __launch_bounds__(256) void sample_kernel(
    const __hip_bfloat16* __restrict__ value,
    const __hip_bfloat16* __restrict__ off, const float* __restrict__ attn,
    __hip_bfloat16* __restrict__ outat) {
  const int s = blockIdx.x & 7;  // slice = b*NH+h; low bits spread XCDs
  const int pidx = blockIdx.x >> 3;
  const int PI = pidx % NPATCH, PJ = pidx / NPATCH;
  const int I0 = PI * PTOK, J0 = PJ * PTOK;
  const int b = s >> 2, h = s & 3;

  __shared__ __hip_bfloat16 patch[PDIM * PDIM][CELLPAD];
  const __hip_bfloat16* vglob = value + (size_t)s * NTOK * DHEAD;

  // stage patch: 256 cells x 64B, zeros outside image
#pragma unroll
  for (int it = 0; it < 4; ++it) {
    int lin = threadIdx.x + 256 * it;  // 0..1023
    int cell = lin >> 2, part = lin & 3;
    int py = cell >> 4, px = cell & 15;
    int gy = J0 - PHALO + py;
    int gx = I0 - PHALO + px;
    short8v v = (short8v)(short)0;
    if (gy >= 0 && gy < HWDIM && gx >= 0 && gx < HWDIM)
      v = *(const short8v*)(vglob + ((size_t)(gy * HWDIM + gx)) * DHEAD +
                            part * 8);
    *(short8v*)&patch[cell][part * 8] = v;
  }
  __syncthreads();

  const int dl = threadIdx.x & 3;    // dim group: 8 dims at dl*8
  const int tok = threadIdx.x >> 2;  // 0..63
  const int li = tok & 7, lj = tok >> 3;
  const int i = I0 + li, j = J0 + lj;
  if (i >= HWDIM || j >= HWDIM) return;
  const int n = i * HWDIM + j;

  // off: 20 packed bf16 (x,y) pairs = 5 int4; attn: 20 f32 = 5 float4
  union { int4 v4[5]; unsigned u[20]; } of;
  union { float4 v4[5]; float f[20]; } at;
  {
    const int4* o4 = (const int4*)(off + ((size_t)s * NTOK + n) * 40);
    const float4* a4 = (const float4*)(attn + ((size_t)s * NTOK + n) * 20);
#pragma unroll
    for (int q = 0; q < 5; ++q) of.v4[q] = o4[q];
#pragma unroll
    for (int q = 0; q < 5; ++q) at.v4[q] = a4[q];
  }

  // softmax exp (no max-sub: logits are small by construction); norm deferred
  float ssum = 0.f;
#pragma unroll
  for (int p = 0; p < NPNT; ++p) {
    at.f[p] = __expf(at.f[p]);
    ssum += at.f[p];
  }
  const float inv = 1.f / ssum;

  const float fi = (float)i, fj = (float)j;
  // four independent accumulator pairs (one per bilinear corner)
  f32x4 c0a = (f32x4)(0.f), c0b = (f32x4)(0.f);
  f32x4 c1a = (f32x4)(0.f), c1b = (f32x4)(0.f);
  f32x4 c2a = (f32x4)(0.f), c2b = (f32x4)(0.f);
  f32x4 c3a = (f32x4)(0.f), c3b = (f32x4)(0.f);
#pragma unroll
  for (int p = 0; p < NPNT; ++p) {
    const unsigned up = of.u[p];
    float x = fi + asf(up << 16);            // i-dim coordinate
    float y = fj + asf(up & 0xFFFF0000u);    // j-dim coordinate
    float aw = at.f[p];                      // un-normalized weight
    float x0f = floorf(x), y0f = floorf(y);
    int ix0 = (int)x0f, iy0 = (int)y0f;
    float wx1 = x - x0f, wy1 = y - y0f;
    float wx0 = 1.f - wx1, wy0 = 1.f - wy1;
    float wya = aw * wy0, wyb = aw * wy1;
    float w00 = wya * wx0, w01 = wya * wx1;
    float w10 = wyb * wx0, w11 = wyb * wx1;
    int ly = iy0 - (J0 - PHALO);
    int lx = ix0 - (I0 - PHALO);
    if (ly >= 0 && ly <= PDIM - 2 && lx >= 0 && lx <= PDIM - 2) {
      const __hip_bfloat16* pb = &patch[ly * PDIM + lx][dl * 8];
      acc_cell(pb, w00, c0a, c0b);
      acc_cell(pb + CELLPAD, w01, c1a, c1b);
      acc_cell(pb + PDIM * CELLPAD, w10, c2a, c2b);
      acc_cell(pb + PDIM * CELLPAD + CELLPAD, w11, c3a, c3b);
    } else {
      // rare out-of-patch fallback: direct gather with bounds checks
      float wgt[4] = {w00, w01, w10, w11};
#pragma unroll
      for (int cy = 0; cy < 2; ++cy) {
        int iy = iy0 + cy;
        if (iy < 0 || iy >= HWDIM) continue;
#pragma unroll
        for (int cx = 0; cx < 2; ++cx) {
          int ix = ix0 + cx;
          if (ix < 0 || ix >= HWDIM) continue;
          acc_cell(vglob + ((size_t)(iy * HWDIM + ix)) * DHEAD + dl * 8,
                   wgt[cy * 2 + cx], c0a, c0b);
        }
      }
    }
  }
  f32x4 a0 = (c0a + c1a) + (c2a + c3a);
  f32x4 a1 = (c0b + c1b) + (c2b + c3b);

  union { short8v v8; __hip_bfloat16 hh[8]; } o;
#pragma unroll
  for (int k = 0; k < 4; ++k) {
    o.hh[k] = __float2bfloat16(a0[k] * inv);
    o.hh[4 + k] = __float2bfloat16(a1[k] * inv);
  }
  *(short8v*)(outat + ((size_t)b * NTOK + n) * CDIM + h * DHEAD + dl * 8) =
      o.v8;
}

extern "C" void kernel_launch(void* const* d_in, const int* in_sizes, int n_in,
                              void* d_out, int out_size, void* d_ws,
                              size_t ws_size, hipStream_t stream) {
  const float* query = (const float*)d_in[0];
  const float* query_pos = (const float*)d_in[1];
  const float* W_val = (const float*)d_in[2];
  const float* b_val = (const float*)d_in[3];
  const float* W_off = (const float*)d_in[4];
  const float* b_off = (const float*)d_in[5];
  const float* W_attn = (const float*)d_in[6];
  const float* b_attn = (const float*)d_in[7];
  const float* W_out1 = (const float*)d_in[8];
  const float* b_out1 = (const float*)d_in[9];
  const float* W_out2 = (const float*)d_in[10];
  const float* b_out2 = (const float*)d_in[11];
  float* out = (float*)d_out;

  char* ws = (char*)d_ws;
  __hip_bfloat16* value = (__hip_bfloat16*)ws;  // (B*NH,N,32) bf16
  ws += (size_t)MROWS * CDIM * 2;
  __hip_bfloat16* offb = (__hip_bfloat16*)ws;   // (B*NH,N,40) bf16
  ws += (size_t)MROWS * 160 * 2;
  float* attnb = (float*)ws;                    // (B*NH,N,20) f32
  ws += (size_t)MROWS * 80 * 4;
  __hip_bfloat16* outat = (__hip_bfloat16*)ws;  // (B,N,C) bf16
  ws += (size_t)MROWS * CDIM * 2;
  float* bc = (float*)ws; ws += 128 * 4;
  float* bcat = (float*)ws; ws += OPAD * 4;
  __hip_bfloat16* Wcat = (__hip_bfloat16*)ws; ws += (size_t)OPAD * 128 * 2;
  __hip_bfloat16* Wc_bf = (__hip_bfloat16*)ws;

  prep_kernel<<<OPAD + 128, 128, 0, stream>>>(
      W_val, b_val, W_off, b_off, W_attn, b_attn, W_out1, b_out1, W_out2,
      b_out2, Wcat, bcat, Wc_bf, bc);

  // proj1: grid (313,2), 3 internal W-tiles each
  mfma_proj_kernel<0, 0><<<dim3(313, 2), 256, 0, stream>>>(
      query, query_pos, nullptr, Wcat, bcat, value, offb, attnb, nullptr,
      nullptr, MROWS, 3, OCAT);

  sample_kernel<<<8 * NPATCH * NPATCH, 256, 0, stream>>>(value, offb, attnb,
                                                         outat);

  // proj2: grid (313,2), 1 tile each
  mfma_proj_kernel<1, 1><<<dim3(313, 2), 256, 0, stream>>>(
      nullptr, nullptr, outat, Wc_bf, bc, nullptr, nullptr, nullptr, out,
      query, MROWS, 1, 128);
}